// Round 4
// baseline (1828.777 us; speedup 1.0000x reference)
//
#include <hip/hip_runtime.h>
#include <math.h>

#define N_NODES 100000
#define N_EDGES 1000000
#define IN_F 128
#define HID 64
#define OUT_F 64
#define NLAYERS 4
#define ALPHA 0.1f
#define BN_EPS 1e-5f

#define SCAN_BLK 256
#define NSCAN_BLOCKS ((N_NODES + SCAN_BLK - 1) / SCAN_BLK)   // 391

// counting sort: 512 rows per bucket, 200 edge chunks
#define BSH 9
#define BROWS (1 << BSH)                                     // 512
#define NBUK ((N_NODES + BROWS - 1) >> BSH)                  // 196
#define P_SCAT 200
#define CHUNK ((N_EDGES + P_SCAT - 1) / P_SCAT)              // 5000

#define NBLK ((N_NODES + 63) / 64)                           // 1563

// ---- workspace layout (bytes) ----
static const size_t OFF_X0       = 0;                       // N*64*4 = 25600000
static const size_t OFF_HA       = 25600000;
static const size_t OFF_HB       = 51200000;                // reused pre-layers: tmp edges + count matrix
static const size_t OFF_GB       = 76800000;                // N*64*2 = 12800000 (bf16, dinv-prescaled)
static const size_t OFF_SORTED   = 89600000;                // E*4 = 4000000
static const size_t OFF_CNT      = 93600000;                // N*4
static const size_t OFF_STATS    = 94000000;                // 512*4 = 2048
static const size_t OFF_DINV     = 94002048;                // N*4
static const size_t OFF_ROWSTART = 94402048;                // (N+1)*4 -> 400016
static const size_t OFF_BSUM     = 95202064;                // 391*4
static const size_t ZERO_OFF     = OFF_CNT;
static const size_t ZERO_BYTES   = 402048;
// inside bufB (dead before layer loop):
static const size_t OFF_TMP_REL  = 0;                       // E*4 packed edges
static const size_t OFF_MAT_REL  = 4000000;                 // P_SCAT*NBUK*4 = 156800

__device__ __forceinline__ unsigned short f2b(float f) {
    unsigned int u = __float_as_uint(f);
    u += 0x7FFFu + ((u >> 16) & 1u);        // round-to-nearest-even
    return (unsigned short)(u >> 16);
}
__device__ __forceinline__ float b2f(unsigned short h) {
    return __uint_as_float(((unsigned int)h) << 16);
}

// fused: per-row degree histogram (global atomics, 100k addrs = low contention)
// + per-(chunk,bucket) LDS histogram for the counting sort partition.
__global__ __launch_bounds__(256) void hist2_kernel(const int* __restrict__ edges,
        int* __restrict__ cnt, int* __restrict__ mat) {
    __shared__ int bh[NBUK];
    int t = threadIdx.x, wg = blockIdx.x;
    for (int j = t; j < NBUK; j += 256) bh[j] = 0;
    __syncthreads();
    int lo = wg * CHUNK, hi = lo + CHUNK; if (hi > N_EDGES) hi = N_EDGES;
    for (int i = lo + t; i < hi; i += 256) {
        int r = edges[i];
        atomicAdd(&cnt[r], 1);
        atomicAdd(&bh[r >> BSH], 1);
    }
    __syncthreads();
    for (int j = t; j < NBUK; j += 256) mat[wg * NBUK + j] = bh[j];
}

__global__ void dinv_kernel(const int* __restrict__ cnt, float* __restrict__ dinv, int n) {
    int i = blockIdx.x * blockDim.x + threadIdx.x;
    if (i < n) {
        int d = cnt[i];
        dinv[i] = d > 0 ? rsqrtf((float)d) : 0.0f;
    }
}

// ---- 3-phase multi-block exclusive scan of cnt -> rs[0..n] ----
__global__ __launch_bounds__(SCAN_BLK) void blocksum_kernel(const int* __restrict__ cnt,
        int* __restrict__ bsum, int n) {
    __shared__ int red[SCAN_BLK / 64];
    int i = blockIdx.x * SCAN_BLK + threadIdx.x;
    int v = (i < n) ? cnt[i] : 0;
#pragma unroll
    for (int off = 32; off > 0; off >>= 1) v += __shfl_down(v, off, 64);
    if ((threadIdx.x & 63) == 0) red[threadIdx.x >> 6] = v;
    __syncthreads();
    if (threadIdx.x == 0) {
        int s = 0;
#pragma unroll
        for (int j = 0; j < SCAN_BLK / 64; ++j) s += red[j];
        bsum[blockIdx.x] = s;
    }
}

__global__ __launch_bounds__(512) void scan_bsum_kernel(int* __restrict__ bsum, int nb) {
    __shared__ int lds[512];
    int t = threadIdx.x;
    lds[t] = (t < nb) ? bsum[t] : 0;
    __syncthreads();
    for (int off = 1; off < 512; off <<= 1) {
        int v = lds[t];
        int add = (t >= off) ? lds[t - off] : 0;
        __syncthreads();
        lds[t] = v + add;
        __syncthreads();
    }
    if (t < nb) bsum[t] = (t == 0) ? 0 : lds[t - 1];
}

__global__ __launch_bounds__(SCAN_BLK) void scan_write_kernel(const int* __restrict__ cnt,
        const int* __restrict__ bsum, int* __restrict__ rs, int n) {
    __shared__ int lds[SCAN_BLK];
    int t = threadIdx.x;
    int i = blockIdx.x * SCAN_BLK + t;
    int c = (i < n) ? cnt[i] : 0;
    lds[t] = c;
    __syncthreads();
    for (int off = 1; off < SCAN_BLK; off <<= 1) {
        int v = lds[t];
        int add = (t >= off) ? lds[t - off] : 0;
        __syncthreads();
        lds[t] = v + add;
        __syncthreads();
    }
    if (i < n) {
        int excl = bsum[blockIdx.x] + lds[t] - c;
        rs[i] = excl;
        if (i == n - 1) rs[n] = excl + c;
    }
}

// column-wise exclusive scan of the (P_SCAT x NBUK) count matrix, seeded with
// each bucket's CSR base.
__global__ __launch_bounds__(256) void matscan_kernel(const int* __restrict__ rs,
        int* __restrict__ mat) {
    int b = threadIdx.x;
    if (b < NBUK) {
        int r = b << BSH; if (r > N_NODES) r = N_NODES;
        int run = rs[r];
        for (int w = 0; w < P_SCAT; ++w) {
            int c = mat[w * NBUK + b];
            mat[w * NBUK + b] = run;
            run += c;
        }
    }
}

// pass 1: deterministic partition. Each WG appends into its PRIVATE per-bucket
// segments via LDS cursors -> no global atomics, full-line combining.
__global__ __launch_bounds__(256) void scatter_pass_kernel(const int* __restrict__ edges,
        const int* __restrict__ mat, unsigned int* __restrict__ tmp) {
    __shared__ int cur[NBUK];
    int t = threadIdx.x, wg = blockIdx.x;
    for (int j = t; j < NBUK; j += 256) cur[j] = mat[wg * NBUK + j];
    __syncthreads();
    int lo = wg * CHUNK, hi = lo + CHUNK; if (hi > N_EDGES) hi = N_EDGES;
    for (int i = lo + t; i < hi; i += 256) {
        int r = edges[i];
        int c = edges[N_EDGES + i];
        int pos = atomicAdd(&cur[r >> BSH], 1);
        tmp[pos] = (unsigned int)c | ((unsigned int)(r & (BROWS - 1)) << 17);
    }
}

// pass 2: one workgroup per bucket; LDS cursor per row. Output keeps the low
// 6 row bits packed with col (col 17b | row%64 << 17) for layerA's flat stream.
__global__ __launch_bounds__(256) void binsort_kernel(const unsigned int* __restrict__ tmp,
        const int* __restrict__ rs, int* __restrict__ scol, int n) {
    __shared__ int lcur[BROWS];
    int b = blockIdx.x;
    int t = threadIdx.x;
    int r0 = b << BSH;
    int rend = r0 + BROWS; if (rend > n) rend = n;
    for (int j = t; j < BROWS; j += 256) {
        int r = r0 + j;
        lcur[j] = (r < n) ? rs[r] : 0;
    }
    __syncthreads();
    int base = rs[r0];
    int end = rs[rend];
    for (int i = base + t; i < end; i += 256) {
        unsigned int p = tmp[i];
        int pos = atomicAdd(&lcur[p >> 17], 1);
        scol[pos] = (int)(p & 0x7FFFFFu);   // col | (row%64)<<17 (buckets 64-aligned)
    }
}

// fc0 as classic LDS-tiled fp32 GEMM: [N,128]@[128,64] + bias, relu, bf16 twin.
__global__ __launch_bounds__(256, 4) void fc0_kernel(const float* __restrict__ x,
        const float* __restrict__ W0, const float* __restrict__ b0,
        const float* __restrict__ dinv, float* __restrict__ out,
        unsigned short* __restrict__ g, int n) {
    __shared__ float At[64][68];   // x^T slice: At[k][r]
    __shared__ float Bt[64][68];   // W0 slice:  Bt[k][c]
    int t = threadIdx.x;
    int base = blockIdx.x * 64;
    int tx = t & 15, ty = t >> 4;
    int r0 = ty * 4, c0 = tx * 4;
    float acc[4][4] = {{0.f}};
    for (int kc = 0; kc < IN_F; kc += 64) {
        __syncthreads();
#pragma unroll
        for (int i = 0; i < 4; ++i) {           // stage x tile (64 rows x 64 k)
            int idx = (i * 256 + t) * 4;
            int r = idx >> 6, kk = idx & 63;
            int rr = base + r; if (rr >= n) rr = n - 1;
            float4 v = *(const float4*)(x + (size_t)rr * IN_F + kc + kk);
            At[kk][r] = v.x; At[kk + 1][r] = v.y; At[kk + 2][r] = v.z; At[kk + 3][r] = v.w;
        }
#pragma unroll
        for (int i = 0; i < 4; ++i) {           // stage W0 slice (64 k x 64 c)
            int idx = (i * 256 + t) * 4;
            int k = idx >> 6, c = idx & 63;
            float4 v = *(const float4*)(W0 + (size_t)(kc + k) * HID + c);
            Bt[k][c] = v.x; Bt[k][c + 1] = v.y; Bt[k][c + 2] = v.z; Bt[k][c + 3] = v.w;
        }
        __syncthreads();
#pragma unroll 4
        for (int k = 0; k < 64; ++k) {
            float4 a = *(const float4*)&At[k][r0];
            float4 b = *(const float4*)&Bt[k][c0];
            acc[0][0] += a.x * b.x; acc[0][1] += a.x * b.y; acc[0][2] += a.x * b.z; acc[0][3] += a.x * b.w;
            acc[1][0] += a.y * b.x; acc[1][1] += a.y * b.y; acc[1][2] += a.y * b.z; acc[1][3] += a.y * b.w;
            acc[2][0] += a.z * b.x; acc[2][1] += a.z * b.y; acc[2][2] += a.z * b.z; acc[2][3] += a.z * b.w;
            acc[3][0] += a.w * b.x; acc[3][1] += a.w * b.y; acc[3][2] += a.w * b.z; acc[3][3] += a.w * b.w;
        }
    }
    float4 bias = *(const float4*)(b0 + c0);
#pragma unroll
    for (int i = 0; i < 4; ++i) {
        int r = base + r0 + i;
        if (r < n) {
            float v0 = acc[i][0] + bias.x; v0 = v0 > 0.f ? v0 : 0.f;
            float v1 = acc[i][1] + bias.y; v1 = v1 > 0.f ? v1 : 0.f;
            float v2 = acc[i][2] + bias.z; v2 = v2 > 0.f ? v2 : 0.f;
            float v3 = acc[i][3] + bias.w; v3 = v3 > 0.f ? v3 : 0.f;
            *(float4*)(out + (size_t)r * HID + c0) = make_float4(v0, v1, v2, v3);
            float dr = dinv[r];
            ushort4 gu;
            gu.x = f2b(dr * v0); gu.y = f2b(dr * v1);
            gu.z = f2b(dr * v2); gu.w = f2b(dr * v3);
            *(ushort4*)(g + (size_t)r * HID + c0) = gu;
        }
    }
}

// fused per-layer kernel, v2: FLAT edge stream. The block's 64 rows own a
// contiguous scol window [rs[base], rs[base+64]); each packed word carries
// col | (row%64)<<17. Waves stream 8 independent edges/iter (no per-row
// dependency chain -> 128 outstanding 128B gathers per CU) and sink into
// At[feature][row] via LDS atomics. Then fix-up (dinv, x0) + dense GEMM +
// BN stats, unchanged.
__global__ __launch_bounds__(256, 4) void layerA_kernel(
        const unsigned short* __restrict__ g, const float* __restrict__ x0,
        const float* __restrict__ dinv, const int* __restrict__ rs,
        const int* __restrict__ scol, const float* __restrict__ cw,
        float* __restrict__ hout, float* __restrict__ stats, float beta, int n) {
    __shared__ float At[64][68];   // s^T tile: At[k][r], accumulated by stream phase
    __shared__ float Bt[64][68];   // cw:       Bt[k][c]
    __shared__ float redS[4][64];
    __shared__ float redQ[4][64];
    int t = threadIdx.x;
    int wave = t >> 6, lane = t & 63;
    int base = blockIdx.x * 64;

#pragma unroll
    for (int i = 0; i < 4; ++i) {               // stage cw (64x64)
        int idx = (i * 256 + t) * 4;
        int k = idx >> 6, c = idx & 63;
        float4 v = *(const float4*)(cw + (size_t)k * HID + c);
        Bt[k][c] = v.x; Bt[k][c + 1] = v.y; Bt[k][c + 2] = v.z; Bt[k][c + 3] = v.w;
    }
    // zero the accumulator tile
    {
        float* a = &At[0][0];
        for (int i = t; i < 64 * 68; i += 256) a[i] = 0.f;
    }
    int rhi = base + 64; if (rhi > n) rhi = n;
    int e0 = rs[base], e1 = rs[rhi];
    __syncthreads();

    // flat edge stream: 8 independent gathers in flight per wave
    for (int e = e0 + wave * 8; e < e1; e += 32) {
        unsigned int pk[8];
        float gv[8];
#pragma unroll
        for (int j = 0; j < 8; ++j) {
            int ee = e + j;
            pk[j] = (unsigned int)scol[ee < e1 ? ee : e1 - 1];
        }
#pragma unroll
        for (int j = 0; j < 8; ++j)
            gv[j] = b2f(g[(size_t)(pk[j] & 0x1FFFFu) * HID + lane]);
#pragma unroll
        for (int j = 0; j < 8; ++j)
            if (e + j < e1) atomicAdd(&At[lane][pk[j] >> 17], gv[j]);
    }
    __syncthreads();

    // fix-up: s = (1-a)*dinv[r]*agg + a*x0[r]
    {
        int rl0 = wave * 16;
#pragma unroll
        for (int i = 0; i < 16; ++i) {
            int rl = rl0 + i;
            int r = base + rl;
            if (r < n) {
                At[lane][rl] = (1.f - ALPHA) * dinv[r] * At[lane][rl]
                             + ALPHA * x0[(size_t)r * HID + lane];
            }
        }
    }
    __syncthreads();

    int tx = t & 15, ty = t >> 4;
    int r0 = ty * 4, c0 = tx * 4;
    float acc[4][4] = {{0.f}};
#pragma unroll 4
    for (int k = 0; k < 64; ++k) {
        float4 a = *(const float4*)&At[k][r0];
        float4 b = *(const float4*)&Bt[k][c0];
        acc[0][0] += a.x * b.x; acc[0][1] += a.x * b.y; acc[0][2] += a.x * b.z; acc[0][3] += a.x * b.w;
        acc[1][0] += a.y * b.x; acc[1][1] += a.y * b.y; acc[1][2] += a.y * b.z; acc[1][3] += a.y * b.w;
        acc[2][0] += a.z * b.x; acc[2][1] += a.z * b.y; acc[2][2] += a.z * b.z; acc[2][3] += a.z * b.w;
        acc[3][0] += a.w * b.x; acc[3][1] += a.w * b.y; acc[3][2] += a.w * b.z; acc[3][3] += a.w * b.w;
    }
    float lsum[4] = {0.f, 0.f, 0.f, 0.f}, lsq[4] = {0.f, 0.f, 0.f, 0.f};
    float ob = 1.f - beta;
#pragma unroll
    for (int i = 0; i < 4; ++i) {
        int r = base + r0 + i;
        if (r < n) {
            float h0 = ob * At[c0][r0 + i]     + beta * acc[i][0];
            float h1 = ob * At[c0 + 1][r0 + i] + beta * acc[i][1];
            float h2 = ob * At[c0 + 2][r0 + i] + beta * acc[i][2];
            float h3 = ob * At[c0 + 3][r0 + i] + beta * acc[i][3];
            *(float4*)(hout + (size_t)r * HID + c0) = make_float4(h0, h1, h2, h3);
            lsum[0] += h0; lsq[0] += h0 * h0;
            lsum[1] += h1; lsq[1] += h1 * h1;
            lsum[2] += h2; lsq[2] += h2 * h2;
            lsum[3] += h3; lsq[3] += h3 * h3;
        }
    }
    // reduce across the 16 threads sharing tx: lanes {tx, tx+16, tx+32, tx+48}
#pragma unroll
    for (int j = 0; j < 4; ++j) {
        float s = lsum[j], q = lsq[j];
        s += __shfl_xor(s, 16, 64); s += __shfl_xor(s, 32, 64);
        q += __shfl_xor(q, 16, 64); q += __shfl_xor(q, 32, 64);
        lsum[j] = s; lsq[j] = q;
    }
    __syncthreads();
    if (lane < 16) {
#pragma unroll
        for (int j = 0; j < 4; ++j) {
            redS[wave][lane * 4 + j] = lsum[j];
            redQ[wave][lane * 4 + j] = lsq[j];
        }
    }
    __syncthreads();
    if (t < 64) {
        float s = redS[0][t] + redS[1][t] + redS[2][t] + redS[3][t];
        float q = redQ[0][t] + redQ[1][t] + redQ[2][t] + redQ[3][t];
        atomicAdd(&stats[t], s);
        atomicAdd(&stats[64 + t], q);
    }
}

// BN + residual + relu in place; also writes next-layer gather twin
__global__ void layerB_kernel(float4* __restrict__ h, const float4* __restrict__ xprev,
        const float* __restrict__ stats, const float* __restrict__ gamma,
        const float* __restrict__ bnb, const float* __restrict__ dinv,
        ushort4* __restrict__ g, int total4) {
    int i = blockIdx.x * blockDim.x + threadIdx.x;
    if (i >= total4) return;
    int fb = (i & 15) * 4;
    int row = i >> 4;
    float dr = dinv[row];
    float4 hv = h[i];
    float4 xp = xprev[i];
    float o[4];
    float hin[4] = { hv.x, hv.y, hv.z, hv.w };
    float xin[4] = { xp.x, xp.y, xp.z, xp.w };
#pragma unroll
    for (int j = 0; j < 4; ++j) {
        int f = fb + j;
        float mu = stats[f] * (1.0f / N_NODES);
        float var = stats[64 + f] * (1.0f / N_NODES) - mu * mu;
        if (var < 0.f) var = 0.f;
        float inv = rsqrtf(var + BN_EPS);
        float v = (hin[j] - mu) * inv * gamma[f] + bnb[f] + xin[j];
        o[j] = v > 0.f ? v : 0.f;
    }
    h[i] = make_float4(o[0], o[1], o[2], o[3]);
    ushort4 gu;
    gu.x = f2b(dr * o[0]); gu.y = f2b(dr * o[1]);
    gu.z = f2b(dr * o[2]); gu.w = f2b(dr * o[3]);
    g[i] = gu;
}

// out = x @ W1 + b1 as LDS-tiled GEMM (K=64, single chunk) + bias epilogue.
__global__ __launch_bounds__(256, 4) void final_kernel(const float* __restrict__ xcur,
        const float* __restrict__ W1, const float* __restrict__ b1,
        float* __restrict__ out, int n) {
    __shared__ float At[64][68];   // x^T tile: At[k][r]
    __shared__ float Bt[64][68];   // W1:       Bt[k][c]
    int t = threadIdx.x;
    int base = blockIdx.x * 64;
    int tx = t & 15, ty = t >> 4;
    int r0 = ty * 4, c0 = tx * 4;
#pragma unroll
    for (int i = 0; i < 4; ++i) {               // stage W1 (64x64)
        int idx = (i * 256 + t) * 4;
        int k = idx >> 6, c = idx & 63;
        float4 v = *(const float4*)(W1 + (size_t)k * OUT_F + c);
        Bt[k][c] = v.x; Bt[k][c + 1] = v.y; Bt[k][c + 2] = v.z; Bt[k][c + 3] = v.w;
    }
#pragma unroll
    for (int i = 0; i < 4; ++i) {               // stage x tile transposed
        int idx = (i * 256 + t) * 4;
        int r = idx >> 6, kk = idx & 63;
        int rr = base + r; if (rr >= n) rr = n - 1;
        float4 v = *(const float4*)(xcur + (size_t)rr * HID + kk);
        At[kk][r] = v.x; At[kk + 1][r] = v.y; At[kk + 2][r] = v.z; At[kk + 3][r] = v.w;
    }
    __syncthreads();
    float acc[4][4] = {{0.f}};
#pragma unroll 4
    for (int k = 0; k < 64; ++k) {
        float4 a = *(const float4*)&At[k][r0];
        float4 b = *(const float4*)&Bt[k][c0];
        acc[0][0] += a.x * b.x; acc[0][1] += a.x * b.y; acc[0][2] += a.x * b.z; acc[0][3] += a.x * b.w;
        acc[1][0] += a.y * b.x; acc[1][1] += a.y * b.y; acc[1][2] += a.y * b.z; acc[1][3] += a.y * b.w;
        acc[2][0] += a.z * b.x; acc[2][1] += a.z * b.y; acc[2][2] += a.z * b.z; acc[2][3] += a.z * b.w;
        acc[3][0] += a.w * b.x; acc[3][1] += a.w * b.y; acc[3][2] += a.w * b.z; acc[3][3] += a.w * b.w;
    }
    float4 bias = *(const float4*)(b1 + c0);
#pragma unroll
    for (int i = 0; i < 4; ++i) {
        int r = base + r0 + i;
        if (r < n) {
            *(float4*)(out + (size_t)r * OUT_F + c0) = make_float4(
                acc[i][0] + bias.x, acc[i][1] + bias.y,
                acc[i][2] + bias.z, acc[i][3] + bias.w);
        }
    }
}

extern "C" void kernel_launch(void* const* d_in, const int* in_sizes, int n_in,
                              void* d_out, int out_size, void* d_ws, size_t ws_size,
                              hipStream_t stream) {
    const float* x     = (const float*)d_in[0];
    const int*   edges = (const int*)d_in[1];
    const float* W0    = (const float*)d_in[2];
    const float* b0    = (const float*)d_in[3];
    const float* cw    = (const float*)d_in[4];
    const float* gamma = (const float*)d_in[5];
    const float* bnb   = (const float*)d_in[6];
    const float* W1    = (const float*)d_in[7];
    const float* b1    = (const float*)d_in[8];
    float* out = (float*)d_out;

    char* ws = (char*)d_ws;
    float* x0    = (float*)(ws + OFF_X0);
    float* bufA  = (float*)(ws + OFF_HA);
    float* bufB  = (float*)(ws + OFF_HB);
    unsigned int* tmp = (unsigned int*)(ws + OFF_HB + OFF_TMP_REL);  // dead before layer loop
    int*   mat   = (int*)(ws + OFF_HB + OFF_MAT_REL);                // dead before layer loop
    unsigned short* gbuf = (unsigned short*)(ws + OFF_GB);
    int*   scol  = (int*)(ws + OFF_SORTED);
    int*   cnt   = (int*)(ws + OFF_CNT);
    float* stats = (float*)(ws + OFF_STATS);
    float* dinv  = (float*)(ws + OFF_DINV);
    int*   rs    = (int*)(ws + OFF_ROWSTART);
    int*   bsum  = (int*)(ws + OFF_BSUM);

    hipMemsetAsync(ws + ZERO_OFF, 0, ZERO_BYTES, stream);
    hist2_kernel<<<P_SCAT, 256, 0, stream>>>(edges, cnt, mat);
    dinv_kernel<<<(N_NODES + 255) / 256, 256, 0, stream>>>(cnt, dinv, N_NODES);
    blocksum_kernel<<<NSCAN_BLOCKS, SCAN_BLK, 0, stream>>>(cnt, bsum, N_NODES);
    scan_bsum_kernel<<<1, 512, 0, stream>>>(bsum, NSCAN_BLOCKS);
    scan_write_kernel<<<NSCAN_BLOCKS, SCAN_BLK, 0, stream>>>(cnt, bsum, rs, N_NODES);
    matscan_kernel<<<1, 256, 0, stream>>>(rs, mat);
    scatter_pass_kernel<<<P_SCAT, 256, 0, stream>>>(edges, mat, tmp);
    binsort_kernel<<<NBUK, 256, 0, stream>>>(tmp, rs, scol, N_NODES);
    fc0_kernel<<<(N_NODES + 63) / 64, 256, 0, stream>>>(x, W0, b0, dinv, x0, gbuf, N_NODES);

    const float* xc = x0;
    float* bufs[2] = { bufA, bufB };
    for (int i = 0; i < NLAYERS; ++i) {
        float beta = logf(0.5f / (float)(i + 1) + 1.0f);
        float* hb = bufs[i & 1];
        layerA_kernel<<<NBLK, 256, 0, stream>>>(gbuf, x0, dinv, rs, scol,
                cw + (size_t)i * HID * HID, hb, stats + i * 128, beta, N_NODES);
        layerB_kernel<<<(N_NODES * HID / 4 + 255) / 256, 256, 0, stream>>>(
                (float4*)hb, (const float4*)xc,
                stats + i * 128, gamma + i * HID, bnb + i * HID, dinv,
                (ushort4*)gbuf, N_NODES * HID / 4);
        xc = hb;
    }
    final_kernel<<<(N_NODES + 63) / 64, 256, 0, stream>>>(xc, W1, b1, out, N_NODES);
}

// Round 5
// 568.633 us; speedup vs baseline: 3.2161x; 3.2161x over previous
//
#include <hip/hip_runtime.h>
#include <math.h>

#define N_NODES 100000
#define N_EDGES 1000000
#define IN_F 128
#define HID 64
#define OUT_F 64
#define NLAYERS 4
#define ALPHA 0.1f
#define BN_EPS 1e-5f

#define SCAN_BLK 256
#define NSCAN_BLOCKS ((N_NODES + SCAN_BLK - 1) / SCAN_BLK)   // 391

// counting sort: 512 rows per bucket, 200 edge chunks
#define BSH 9
#define BROWS (1 << BSH)                                     // 512
#define NBUK ((N_NODES + BROWS - 1) >> BSH)                  // 196
#define P_SCAT 200
#define CHUNK ((N_EDGES + P_SCAT - 1) / P_SCAT)              // 5000

#define NBLK ((N_NODES + 63) / 64)                           // 1563

// ---- workspace layout (bytes) ----
static const size_t OFF_X0       = 0;                       // N*64*4 = 25600000
static const size_t OFF_HA       = 25600000;
static const size_t OFF_HB       = 51200000;                // reused pre-layers: tmp edges + count matrix
static const size_t OFF_GB       = 76800000;                // N*64*2 = 12800000 (bf16, dinv-prescaled)
static const size_t OFF_SORTED   = 89600000;                // E*4 = 4000000
static const size_t OFF_CNT      = 93600000;                // N*4
static const size_t OFF_STATS    = 94000000;                // 512*4 = 2048
static const size_t OFF_DINV     = 94002048;                // N*4
static const size_t OFF_ROWSTART = 94402048;                // (N+1)*4 -> 400016
static const size_t OFF_BSUM     = 95202064;                // 391*4
static const size_t ZERO_OFF     = OFF_CNT;
static const size_t ZERO_BYTES   = 402048;
// inside bufB (dead before layer loop):
static const size_t OFF_TMP_REL  = 0;                       // E*4 packed edges
static const size_t OFF_MAT_REL  = 4000000;                 // P_SCAT*NBUK*4 = 156800

__device__ __forceinline__ unsigned short f2b(float f) {
    unsigned int u = __float_as_uint(f);
    u += 0x7FFFu + ((u >> 16) & 1u);        // round-to-nearest-even
    return (unsigned short)(u >> 16);
}
__device__ __forceinline__ float b2f(unsigned short h) {
    return __uint_as_float(((unsigned int)h) << 16);
}

// fused: per-row degree histogram (global atomics, 100k addrs = low contention)
// + per-(chunk,bucket) LDS histogram for the counting sort partition.
__global__ __launch_bounds__(256) void hist2_kernel(const int* __restrict__ edges,
        int* __restrict__ cnt, int* __restrict__ mat) {
    __shared__ int bh[NBUK];
    int t = threadIdx.x, wg = blockIdx.x;
    for (int j = t; j < NBUK; j += 256) bh[j] = 0;
    __syncthreads();
    int lo = wg * CHUNK, hi = lo + CHUNK; if (hi > N_EDGES) hi = N_EDGES;
    for (int i = lo + t; i < hi; i += 256) {
        int r = edges[i];
        atomicAdd(&cnt[r], 1);
        atomicAdd(&bh[r >> BSH], 1);
    }
    __syncthreads();
    for (int j = t; j < NBUK; j += 256) mat[wg * NBUK + j] = bh[j];
}

__global__ void dinv_kernel(const int* __restrict__ cnt, float* __restrict__ dinv, int n) {
    int i = blockIdx.x * blockDim.x + threadIdx.x;
    if (i < n) {
        int d = cnt[i];
        dinv[i] = d > 0 ? rsqrtf((float)d) : 0.0f;
    }
}

// ---- 3-phase multi-block exclusive scan of cnt -> rs[0..n] ----
__global__ __launch_bounds__(SCAN_BLK) void blocksum_kernel(const int* __restrict__ cnt,
        int* __restrict__ bsum, int n) {
    __shared__ int red[SCAN_BLK / 64];
    int i = blockIdx.x * SCAN_BLK + threadIdx.x;
    int v = (i < n) ? cnt[i] : 0;
#pragma unroll
    for (int off = 32; off > 0; off >>= 1) v += __shfl_down(v, off, 64);
    if ((threadIdx.x & 63) == 0) red[threadIdx.x >> 6] = v;
    __syncthreads();
    if (threadIdx.x == 0) {
        int s = 0;
#pragma unroll
        for (int j = 0; j < SCAN_BLK / 64; ++j) s += red[j];
        bsum[blockIdx.x] = s;
    }
}

__global__ __launch_bounds__(512) void scan_bsum_kernel(int* __restrict__ bsum, int nb) {
    __shared__ int lds[512];
    int t = threadIdx.x;
    lds[t] = (t < nb) ? bsum[t] : 0;
    __syncthreads();
    for (int off = 1; off < 512; off <<= 1) {
        int v = lds[t];
        int add = (t >= off) ? lds[t - off] : 0;
        __syncthreads();
        lds[t] = v + add;
        __syncthreads();
    }
    if (t < nb) bsum[t] = (t == 0) ? 0 : lds[t - 1];
}

__global__ __launch_bounds__(SCAN_BLK) void scan_write_kernel(const int* __restrict__ cnt,
        const int* __restrict__ bsum, int* __restrict__ rs, int n) {
    __shared__ int lds[SCAN_BLK];
    int t = threadIdx.x;
    int i = blockIdx.x * SCAN_BLK + t;
    int c = (i < n) ? cnt[i] : 0;
    lds[t] = c;
    __syncthreads();
    for (int off = 1; off < SCAN_BLK; off <<= 1) {
        int v = lds[t];
        int add = (t >= off) ? lds[t - off] : 0;
        __syncthreads();
        lds[t] = v + add;
        __syncthreads();
    }
    if (i < n) {
        int excl = bsum[blockIdx.x] + lds[t] - c;
        rs[i] = excl;
        if (i == n - 1) rs[n] = excl + c;
    }
}

// column-wise exclusive scan of the (P_SCAT x NBUK) count matrix, seeded with
// each bucket's CSR base.
__global__ __launch_bounds__(256) void matscan_kernel(const int* __restrict__ rs,
        int* __restrict__ mat) {
    int b = threadIdx.x;
    if (b < NBUK) {
        int r = b << BSH; if (r > N_NODES) r = N_NODES;
        int run = rs[r];
        for (int w = 0; w < P_SCAT; ++w) {
            int c = mat[w * NBUK + b];
            mat[w * NBUK + b] = run;
            run += c;
        }
    }
}

// pass 1: deterministic partition. Each WG appends into its PRIVATE per-bucket
// segments via LDS cursors -> no global atomics, full-line combining.
__global__ __launch_bounds__(256) void scatter_pass_kernel(const int* __restrict__ edges,
        const int* __restrict__ mat, unsigned int* __restrict__ tmp) {
    __shared__ int cur[NBUK];
    int t = threadIdx.x, wg = blockIdx.x;
    for (int j = t; j < NBUK; j += 256) cur[j] = mat[wg * NBUK + j];
    __syncthreads();
    int lo = wg * CHUNK, hi = lo + CHUNK; if (hi > N_EDGES) hi = N_EDGES;
    for (int i = lo + t; i < hi; i += 256) {
        int r = edges[i];
        int c = edges[N_EDGES + i];
        int pos = atomicAdd(&cur[r >> BSH], 1);
        tmp[pos] = (unsigned int)c | ((unsigned int)(r & (BROWS - 1)) << 17);
    }
}

// pass 2: one workgroup per bucket; LDS cursor per row. Output keeps the low
// 6 row bits packed with col (col 17b | row%64 << 17) for layerA's flat stream.
__global__ __launch_bounds__(256) void binsort_kernel(const unsigned int* __restrict__ tmp,
        const int* __restrict__ rs, int* __restrict__ scol, int n) {
    __shared__ int lcur[BROWS];
    int b = blockIdx.x;
    int t = threadIdx.x;
    int r0 = b << BSH;
    int rend = r0 + BROWS; if (rend > n) rend = n;
    for (int j = t; j < BROWS; j += 256) {
        int r = r0 + j;
        lcur[j] = (r < n) ? rs[r] : 0;
    }
    __syncthreads();
    int base = rs[r0];
    int end = rs[rend];
    for (int i = base + t; i < end; i += 256) {
        unsigned int p = tmp[i];
        int pos = atomicAdd(&lcur[p >> 17], 1);
        scol[pos] = (int)(p & 0x7FFFFFu);   // col | (row%64)<<17 (buckets 64-aligned)
    }
}

// fc0 as classic LDS-tiled fp32 GEMM: [N,128]@[128,64] + bias, relu, bf16 twin.
__global__ __launch_bounds__(256, 4) void fc0_kernel(const float* __restrict__ x,
        const float* __restrict__ W0, const float* __restrict__ b0,
        const float* __restrict__ dinv, float* __restrict__ out,
        unsigned short* __restrict__ g, int n) {
    __shared__ float At[64][68];   // x^T slice: At[k][r]
    __shared__ float Bt[64][68];   // W0 slice:  Bt[k][c]
    int t = threadIdx.x;
    int base = blockIdx.x * 64;
    int tx = t & 15, ty = t >> 4;
    int r0 = ty * 4, c0 = tx * 4;
    float acc[4][4] = {{0.f}};
    for (int kc = 0; kc < IN_F; kc += 64) {
        __syncthreads();
#pragma unroll
        for (int i = 0; i < 4; ++i) {           // stage x tile (64 rows x 64 k)
            int idx = (i * 256 + t) * 4;
            int r = idx >> 6, kk = idx & 63;
            int rr = base + r; if (rr >= n) rr = n - 1;
            float4 v = *(const float4*)(x + (size_t)rr * IN_F + kc + kk);
            At[kk][r] = v.x; At[kk + 1][r] = v.y; At[kk + 2][r] = v.z; At[kk + 3][r] = v.w;
        }
#pragma unroll
        for (int i = 0; i < 4; ++i) {           // stage W0 slice (64 k x 64 c)
            int idx = (i * 256 + t) * 4;
            int k = idx >> 6, c = idx & 63;
            float4 v = *(const float4*)(W0 + (size_t)(kc + k) * HID + c);
            Bt[k][c] = v.x; Bt[k][c + 1] = v.y; Bt[k][c + 2] = v.z; Bt[k][c + 3] = v.w;
        }
        __syncthreads();
#pragma unroll 4
        for (int k = 0; k < 64; ++k) {
            float4 a = *(const float4*)&At[k][r0];
            float4 b = *(const float4*)&Bt[k][c0];
            acc[0][0] += a.x * b.x; acc[0][1] += a.x * b.y; acc[0][2] += a.x * b.z; acc[0][3] += a.x * b.w;
            acc[1][0] += a.y * b.x; acc[1][1] += a.y * b.y; acc[1][2] += a.y * b.z; acc[1][3] += a.y * b.w;
            acc[2][0] += a.z * b.x; acc[2][1] += a.z * b.y; acc[2][2] += a.z * b.z; acc[2][3] += a.z * b.w;
            acc[3][0] += a.w * b.x; acc[3][1] += a.w * b.y; acc[3][2] += a.w * b.z; acc[3][3] += a.w * b.w;
        }
    }
    float4 bias = *(const float4*)(b0 + c0);
#pragma unroll
    for (int i = 0; i < 4; ++i) {
        int r = base + r0 + i;
        if (r < n) {
            float v0 = acc[i][0] + bias.x; v0 = v0 > 0.f ? v0 : 0.f;
            float v1 = acc[i][1] + bias.y; v1 = v1 > 0.f ? v1 : 0.f;
            float v2 = acc[i][2] + bias.z; v2 = v2 > 0.f ? v2 : 0.f;
            float v3 = acc[i][3] + bias.w; v3 = v3 > 0.f ? v3 : 0.f;
            *(float4*)(out + (size_t)r * HID + c0) = make_float4(v0, v1, v2, v3);
            float dr = dinv[r];
            ushort4 gu;
            gu.x = f2b(dr * v0); gu.y = f2b(dr * v1);
            gu.z = f2b(dr * v2); gu.w = f2b(dr * v3);
            *(ushort4*)(g + (size_t)r * HID + c0) = gu;
        }
    }
}

// fused per-layer kernel, v3: flat edge stream with REGISTER accumulation.
// Quarter-wave decomposition: wave covers 16 rows; each 16-lane quarter owns
// 4 consecutive rows as ONE contiguous edge window (row-sorted). Lane l owns
// features 4l..4l+3 (ushort4 gather; 16 lanes = full 128B line). Row-sorted
// stream + running float4 acc + plain LDS store on row-change: no atomics,
// 32 independent gathers in flight per wave (4 quarters x 8-deep unroll).
__global__ __launch_bounds__(256, 4) void layerA_kernel(
        const unsigned short* __restrict__ g, const float* __restrict__ x0,
        const float* __restrict__ dinv, const int* __restrict__ rs,
        const int* __restrict__ scol, const float* __restrict__ cw,
        float* __restrict__ hout, float* __restrict__ stats, float beta, int n) {
    __shared__ float At[64][68];   // s^T tile: At[k][r]
    __shared__ float Bt[64][68];   // cw:       Bt[k][c]
    __shared__ float redS[4][64];
    __shared__ float redQ[4][64];
    int t = threadIdx.x;
    int wave = t >> 6, lane = t & 63;
    int base = blockIdx.x * 64;

#pragma unroll
    for (int i = 0; i < 4; ++i) {               // stage cw (64x64)
        int idx = (i * 256 + t) * 4;
        int k = idx >> 6, c = idx & 63;
        float4 v = *(const float4*)(cw + (size_t)k * HID + c);
        Bt[k][c] = v.x; Bt[k][c + 1] = v.y; Bt[k][c + 2] = v.z; Bt[k][c + 3] = v.w;
    }
    // zero the accumulator tile (covers zero-degree rows)
    {
        float* a = &At[0][0];
        for (int i = t; i < 64 * 68; i += 256) a[i] = 0.f;
    }
    __syncthreads();

    // flat-stream gather, register accumulation
    {
        int q = lane >> 4, l = lane & 15;
        int rq = base + wave * 16 + q * 4;       // first row of this quarter
        int rqe = rq + 4;
        if (rq > n) rq = n;
        if (rqe > n) rqe = n;
        int e = rs[rq], eend = rs[rqe];
        float4 acc4 = make_float4(0.f, 0.f, 0.f, 0.f);
        int cur = -1;
        for (; e < eend; e += 8) {
            unsigned int pk[8];
            ushort4 gv[8];
#pragma unroll
            for (int j = 0; j < 8; ++j) {
                int ee = e + j;
                pk[j] = (unsigned int)scol[ee < eend ? ee : eend - 1];
            }
#pragma unroll
            for (int j = 0; j < 8; ++j)
                gv[j] = *(const ushort4*)(g + (size_t)(pk[j] & 0x1FFFFu) * HID + l * 4);
#pragma unroll
            for (int j = 0; j < 8; ++j) {
                if (e + j < eend) {
                    int rj = (int)(pk[j] >> 17);
                    if (rj != cur) {
                        if (cur >= 0) {
                            At[l * 4 + 0][cur] = acc4.x;
                            At[l * 4 + 1][cur] = acc4.y;
                            At[l * 4 + 2][cur] = acc4.z;
                            At[l * 4 + 3][cur] = acc4.w;
                        }
                        acc4 = make_float4(0.f, 0.f, 0.f, 0.f);
                        cur = rj;
                    }
                    acc4.x += b2f(gv[j].x);
                    acc4.y += b2f(gv[j].y);
                    acc4.z += b2f(gv[j].z);
                    acc4.w += b2f(gv[j].w);
                }
            }
        }
        if (cur >= 0) {
            At[l * 4 + 0][cur] = acc4.x;
            At[l * 4 + 1][cur] = acc4.y;
            At[l * 4 + 2][cur] = acc4.z;
            At[l * 4 + 3][cur] = acc4.w;
        }
    }
    __syncthreads();

    // fix-up: s = (1-a)*dinv[r]*agg + a*x0[r]
    {
        int rl0 = wave * 16;
#pragma unroll
        for (int i = 0; i < 16; ++i) {
            int rl = rl0 + i;
            int r = base + rl;
            if (r < n) {
                At[lane][rl] = (1.f - ALPHA) * dinv[r] * At[lane][rl]
                             + ALPHA * x0[(size_t)r * HID + lane];
            }
        }
    }
    __syncthreads();

    int tx = t & 15, ty = t >> 4;
    int r0 = ty * 4, c0 = tx * 4;
    float acc[4][4] = {{0.f}};
#pragma unroll 4
    for (int k = 0; k < 64; ++k) {
        float4 a = *(const float4*)&At[k][r0];
        float4 b = *(const float4*)&Bt[k][c0];
        acc[0][0] += a.x * b.x; acc[0][1] += a.x * b.y; acc[0][2] += a.x * b.z; acc[0][3] += a.x * b.w;
        acc[1][0] += a.y * b.x; acc[1][1] += a.y * b.y; acc[1][2] += a.y * b.z; acc[1][3] += a.y * b.w;
        acc[2][0] += a.z * b.x; acc[2][1] += a.z * b.y; acc[2][2] += a.z * b.z; acc[2][3] += a.z * b.w;
        acc[3][0] += a.w * b.x; acc[3][1] += a.w * b.y; acc[3][2] += a.w * b.z; acc[3][3] += a.w * b.w;
    }
    float lsum[4] = {0.f, 0.f, 0.f, 0.f}, lsq[4] = {0.f, 0.f, 0.f, 0.f};
    float ob = 1.f - beta;
#pragma unroll
    for (int i = 0; i < 4; ++i) {
        int r = base + r0 + i;
        if (r < n) {
            float h0 = ob * At[c0][r0 + i]     + beta * acc[i][0];
            float h1 = ob * At[c0 + 1][r0 + i] + beta * acc[i][1];
            float h2 = ob * At[c0 + 2][r0 + i] + beta * acc[i][2];
            float h3 = ob * At[c0 + 3][r0 + i] + beta * acc[i][3];
            *(float4*)(hout + (size_t)r * HID + c0) = make_float4(h0, h1, h2, h3);
            lsum[0] += h0; lsq[0] += h0 * h0;
            lsum[1] += h1; lsq[1] += h1 * h1;
            lsum[2] += h2; lsq[2] += h2 * h2;
            lsum[3] += h3; lsq[3] += h3 * h3;
        }
    }
    // reduce across the 16 threads sharing tx: lanes {tx, tx+16, tx+32, tx+48}
#pragma unroll
    for (int j = 0; j < 4; ++j) {
        float s = lsum[j], q = lsq[j];
        s += __shfl_xor(s, 16, 64); s += __shfl_xor(s, 32, 64);
        q += __shfl_xor(q, 16, 64); q += __shfl_xor(q, 32, 64);
        lsum[j] = s; lsq[j] = q;
    }
    __syncthreads();
    if (lane < 16) {
#pragma unroll
        for (int j = 0; j < 4; ++j) {
            redS[wave][lane * 4 + j] = lsum[j];
            redQ[wave][lane * 4 + j] = lsq[j];
        }
    }
    __syncthreads();
    if (t < 64) {
        float s = redS[0][t] + redS[1][t] + redS[2][t] + redS[3][t];
        float q = redQ[0][t] + redQ[1][t] + redQ[2][t] + redQ[3][t];
        atomicAdd(&stats[t], s);
        atomicAdd(&stats[64 + t], q);
    }
}

// BN + residual + relu in place; also writes next-layer gather twin
__global__ void layerB_kernel(float4* __restrict__ h, const float4* __restrict__ xprev,
        const float* __restrict__ stats, const float* __restrict__ gamma,
        const float* __restrict__ bnb, const float* __restrict__ dinv,
        ushort4* __restrict__ g, int total4) {
    int i = blockIdx.x * blockDim.x + threadIdx.x;
    if (i >= total4) return;
    int fb = (i & 15) * 4;
    int row = i >> 4;
    float dr = dinv[row];
    float4 hv = h[i];
    float4 xp = xprev[i];
    float o[4];
    float hin[4] = { hv.x, hv.y, hv.z, hv.w };
    float xin[4] = { xp.x, xp.y, xp.z, xp.w };
#pragma unroll
    for (int j = 0; j < 4; ++j) {
        int f = fb + j;
        float mu = stats[f] * (1.0f / N_NODES);
        float var = stats[64 + f] * (1.0f / N_NODES) - mu * mu;
        if (var < 0.f) var = 0.f;
        float inv = rsqrtf(var + BN_EPS);
        float v = (hin[j] - mu) * inv * gamma[f] + bnb[f] + xin[j];
        o[j] = v > 0.f ? v : 0.f;
    }
    h[i] = make_float4(o[0], o[1], o[2], o[3]);
    ushort4 gu;
    gu.x = f2b(dr * o[0]); gu.y = f2b(dr * o[1]);
    gu.z = f2b(dr * o[2]); gu.w = f2b(dr * o[3]);
    g[i] = gu;
}

// out = x @ W1 + b1 as LDS-tiled GEMM (K=64, single chunk) + bias epilogue.
__global__ __launch_bounds__(256, 4) void final_kernel(const float* __restrict__ xcur,
        const float* __restrict__ W1, const float* __restrict__ b1,
        float* __restrict__ out, int n) {
    __shared__ float At[64][68];   // x^T tile: At[k][r]
    __shared__ float Bt[64][68];   // W1:       Bt[k][c]
    int t = threadIdx.x;
    int base = blockIdx.x * 64;
    int tx = t & 15, ty = t >> 4;
    int r0 = ty * 4, c0 = tx * 4;
#pragma unroll
    for (int i = 0; i < 4; ++i) {               // stage W1 (64x64)
        int idx = (i * 256 + t) * 4;
        int k = idx >> 6, c = idx & 63;
        float4 v = *(const float4*)(W1 + (size_t)k * OUT_F + c);
        Bt[k][c] = v.x; Bt[k][c + 1] = v.y; Bt[k][c + 2] = v.z; Bt[k][c + 3] = v.w;
    }
#pragma unroll
    for (int i = 0; i < 4; ++i) {               // stage x tile transposed
        int idx = (i * 256 + t) * 4;
        int r = idx >> 6, kk = idx & 63;
        int rr = base + r; if (rr >= n) rr = n - 1;
        float4 v = *(const float4*)(xcur + (size_t)rr * HID + kk);
        At[kk][r] = v.x; At[kk + 1][r] = v.y; At[kk + 2][r] = v.z; At[kk + 3][r] = v.w;
    }
    __syncthreads();
    float acc[4][4] = {{0.f}};
#pragma unroll 4
    for (int k = 0; k < 64; ++k) {
        float4 a = *(const float4*)&At[k][r0];
        float4 b = *(const float4*)&Bt[k][c0];
        acc[0][0] += a.x * b.x; acc[0][1] += a.x * b.y; acc[0][2] += a.x * b.z; acc[0][3] += a.x * b.w;
        acc[1][0] += a.y * b.x; acc[1][1] += a.y * b.y; acc[1][2] += a.y * b.z; acc[1][3] += a.y * b.w;
        acc[2][0] += a.z * b.x; acc[2][1] += a.z * b.y; acc[2][2] += a.z * b.z; acc[2][3] += a.z * b.w;
        acc[3][0] += a.w * b.x; acc[3][1] += a.w * b.y; acc[3][2] += a.w * b.z; acc[3][3] += a.w * b.w;
    }
    float4 bias = *(const float4*)(b1 + c0);
#pragma unroll
    for (int i = 0; i < 4; ++i) {
        int r = base + r0 + i;
        if (r < n) {
            *(float4*)(out + (size_t)r * OUT_F + c0) = make_float4(
                acc[i][0] + bias.x, acc[i][1] + bias.y,
                acc[i][2] + bias.z, acc[i][3] + bias.w);
        }
    }
}

extern "C" void kernel_launch(void* const* d_in, const int* in_sizes, int n_in,
                              void* d_out, int out_size, void* d_ws, size_t ws_size,
                              hipStream_t stream) {
    const float* x     = (const float*)d_in[0];
    const int*   edges = (const int*)d_in[1];
    const float* W0    = (const float*)d_in[2];
    const float* b0    = (const float*)d_in[3];
    const float* cw    = (const float*)d_in[4];
    const float* gamma = (const float*)d_in[5];
    const float* bnb   = (const float*)d_in[6];
    const float* W1    = (const float*)d_in[7];
    const float* b1    = (const float*)d_in[8];
    float* out = (float*)d_out;

    char* ws = (char*)d_ws;
    float* x0    = (float*)(ws + OFF_X0);
    float* bufA  = (float*)(ws + OFF_HA);
    float* bufB  = (float*)(ws + OFF_HB);
    unsigned int* tmp = (unsigned int*)(ws + OFF_HB + OFF_TMP_REL);  // dead before layer loop
    int*   mat   = (int*)(ws + OFF_HB + OFF_MAT_REL);                // dead before layer loop
    unsigned short* gbuf = (unsigned short*)(ws + OFF_GB);
    int*   scol  = (int*)(ws + OFF_SORTED);
    int*   cnt   = (int*)(ws + OFF_CNT);
    float* stats = (float*)(ws + OFF_STATS);
    float* dinv  = (float*)(ws + OFF_DINV);
    int*   rs    = (int*)(ws + OFF_ROWSTART);
    int*   bsum  = (int*)(ws + OFF_BSUM);

    hipMemsetAsync(ws + ZERO_OFF, 0, ZERO_BYTES, stream);
    hist2_kernel<<<P_SCAT, 256, 0, stream>>>(edges, cnt, mat);
    dinv_kernel<<<(N_NODES + 255) / 256, 256, 0, stream>>>(cnt, dinv, N_NODES);
    blocksum_kernel<<<NSCAN_BLOCKS, SCAN_BLK, 0, stream>>>(cnt, bsum, N_NODES);
    scan_bsum_kernel<<<1, 512, 0, stream>>>(bsum, NSCAN_BLOCKS);
    scan_write_kernel<<<NSCAN_BLOCKS, SCAN_BLK, 0, stream>>>(cnt, bsum, rs, N_NODES);
    matscan_kernel<<<1, 256, 0, stream>>>(rs, mat);
    scatter_pass_kernel<<<P_SCAT, 256, 0, stream>>>(edges, mat, tmp);
    binsort_kernel<<<NBUK, 256, 0, stream>>>(tmp, rs, scol, N_NODES);
    fc0_kernel<<<(N_NODES + 63) / 64, 256, 0, stream>>>(x, W0, b0, dinv, x0, gbuf, N_NODES);

    const float* xc = x0;
    float* bufs[2] = { bufA, bufB };
    for (int i = 0; i < NLAYERS; ++i) {
        float beta = logf(0.5f / (float)(i + 1) + 1.0f);
        float* hb = bufs[i & 1];
        layerA_kernel<<<NBLK, 256, 0, stream>>>(gbuf, x0, dinv, rs, scol,
                cw + (size_t)i * HID * HID, hb, stats + i * 128, beta, N_NODES);
        layerB_kernel<<<(N_NODES * HID / 4 + 255) / 256, 256, 0, stream>>>(
                (float4*)hb, (const float4*)xc,
                stats + i * 128, gamma + i * HID, bnb + i * HID, dinv,
                (ushort4*)gbuf, N_NODES * HID / 4);
        xc = hb;
    }
    final_kernel<<<(N_NODES + 63) / 64, 256, 0, stream>>>(xc, W1, b1, out, N_NODES);
}

// Round 6
// 551.248 us; speedup vs baseline: 3.3175x; 1.0315x over previous
//
#include <hip/hip_runtime.h>
#include <math.h>

#define N_NODES 100000
#define N_EDGES 1000000
#define IN_F 128
#define HID 64
#define OUT_F 64
#define NLAYERS 4
#define ALPHA 0.1f
#define BN_EPS 1e-5f

#define SCAN_BLK 256
#define NSCAN_BLOCKS ((N_NODES + SCAN_BLK - 1) / SCAN_BLK)   // 391

// counting sort: 512 rows per bucket, 200 edge chunks
#define BSH 9
#define BROWS (1 << BSH)                                     // 512
#define NBUK ((N_NODES + BROWS - 1) >> BSH)                  // 196
#define P_SCAT 200
#define CHUNK ((N_EDGES + P_SCAT - 1) / P_SCAT)              // 5000

#define NBLK ((N_NODES + 63) / 64)                           // 1563

// ---- workspace layout (bytes) ----
static const size_t OFF_X0       = 0;                       // N*64*4 = 25600000
static const size_t OFF_HA       = 25600000;
static const size_t OFF_HB       = 51200000;                // reused pre-layers: tmp edges + count matrix
static const size_t OFF_GB       = 76800000;                // N*64*2 = 12800000 (bf16, dinv-prescaled)
static const size_t OFF_SORTED   = 89600000;                // E*4 = 4000000
static const size_t OFF_CNT      = 93600000;                // N*4
static const size_t OFF_STATS    = 94000000;                // 512*4 = 2048
static const size_t OFF_DINV     = 94002048;                // N*4
static const size_t OFF_ROWSTART = 94402048;                // (N+1)*4 -> 400016
static const size_t OFF_BSUM     = 95202064;                // 391*4
static const size_t ZERO_OFF     = OFF_CNT;
static const size_t ZERO_BYTES   = 402048;
// inside bufB (dead before layer loop):
static const size_t OFF_TMP_REL  = 0;                       // E*4 packed edges
static const size_t OFF_MAT_REL  = 4000000;                 // P_SCAT*NBUK*4 = 156800

__device__ __forceinline__ unsigned short f2b(float f) {
    unsigned int u = __float_as_uint(f);
    u += 0x7FFFu + ((u >> 16) & 1u);        // round-to-nearest-even
    return (unsigned short)(u >> 16);
}
__device__ __forceinline__ float b2f(unsigned short h) {
    return __uint_as_float(((unsigned int)h) << 16);
}

// fused: per-row degree histogram (global atomics, 100k addrs = low contention)
// + per-(chunk,bucket) LDS histogram for the counting sort partition.
__global__ __launch_bounds__(256) void hist2_kernel(const int* __restrict__ edges,
        int* __restrict__ cnt, int* __restrict__ mat) {
    __shared__ int bh[NBUK];
    int t = threadIdx.x, wg = blockIdx.x;
    for (int j = t; j < NBUK; j += 256) bh[j] = 0;
    __syncthreads();
    int lo = wg * CHUNK, hi = lo + CHUNK; if (hi > N_EDGES) hi = N_EDGES;
    for (int i = lo + t; i < hi; i += 256) {
        int r = edges[i];
        atomicAdd(&cnt[r], 1);
        atomicAdd(&bh[r >> BSH], 1);
    }
    __syncthreads();
    for (int j = t; j < NBUK; j += 256) mat[wg * NBUK + j] = bh[j];
}

__global__ void dinv_kernel(const int* __restrict__ cnt, float* __restrict__ dinv, int n) {
    int i = blockIdx.x * blockDim.x + threadIdx.x;
    if (i < n) {
        int d = cnt[i];
        dinv[i] = d > 0 ? rsqrtf((float)d) : 0.0f;
    }
}

// ---- 3-phase multi-block exclusive scan of cnt -> rs[0..n] ----
__global__ __launch_bounds__(SCAN_BLK) void blocksum_kernel(const int* __restrict__ cnt,
        int* __restrict__ bsum, int n) {
    __shared__ int red[SCAN_BLK / 64];
    int i = blockIdx.x * SCAN_BLK + threadIdx.x;
    int v = (i < n) ? cnt[i] : 0;
#pragma unroll
    for (int off = 32; off > 0; off >>= 1) v += __shfl_down(v, off, 64);
    if ((threadIdx.x & 63) == 0) red[threadIdx.x >> 6] = v;
    __syncthreads();
    if (threadIdx.x == 0) {
        int s = 0;
#pragma unroll
        for (int j = 0; j < SCAN_BLK / 64; ++j) s += red[j];
        bsum[blockIdx.x] = s;
    }
}

__global__ __launch_bounds__(512) void scan_bsum_kernel(int* __restrict__ bsum, int nb) {
    __shared__ int lds[512];
    int t = threadIdx.x;
    lds[t] = (t < nb) ? bsum[t] : 0;
    __syncthreads();
    for (int off = 1; off < 512; off <<= 1) {
        int v = lds[t];
        int add = (t >= off) ? lds[t - off] : 0;
        __syncthreads();
        lds[t] = v + add;
        __syncthreads();
    }
    if (t < nb) bsum[t] = (t == 0) ? 0 : lds[t - 1];
}

__global__ __launch_bounds__(SCAN_BLK) void scan_write_kernel(const int* __restrict__ cnt,
        const int* __restrict__ bsum, int* __restrict__ rs, int n) {
    __shared__ int lds[SCAN_BLK];
    int t = threadIdx.x;
    int i = blockIdx.x * SCAN_BLK + t;
    int c = (i < n) ? cnt[i] : 0;
    lds[t] = c;
    __syncthreads();
    for (int off = 1; off < SCAN_BLK; off <<= 1) {
        int v = lds[t];
        int add = (t >= off) ? lds[t - off] : 0;
        __syncthreads();
        lds[t] = v + add;
        __syncthreads();
    }
    if (i < n) {
        int excl = bsum[blockIdx.x] + lds[t] - c;
        rs[i] = excl;
        if (i == n - 1) rs[n] = excl + c;
    }
}

// parallel column scan: one block per bucket; 256-wide LDS Hillis-Steele scan
// over the 200 chunk-counts, seeded with the bucket's CSR base. Replaces the
// old single-block serial column walk (200-deep dependent-load chain).
__global__ __launch_bounds__(256) void matscan_kernel(const int* __restrict__ rs,
        int* __restrict__ mat) {
    __shared__ int lds[256];
    int b = blockIdx.x;
    int t = threadIdx.x;
    int v = (t < P_SCAT) ? mat[t * NBUK + b] : 0;
    lds[t] = v;
    __syncthreads();
    for (int off = 1; off < 256; off <<= 1) {
        int x = lds[t];
        int add = (t >= off) ? lds[t - off] : 0;
        __syncthreads();
        lds[t] = x + add;
        __syncthreads();
    }
    if (t < P_SCAT) {
        int seed = rs[b << BSH];
        mat[t * NBUK + b] = seed + lds[t] - v;   // exclusive + seed
    }
}

// pass 1: deterministic partition. Each WG appends into its PRIVATE per-bucket
// segments via LDS cursors -> no global atomics, full-line combining.
__global__ __launch_bounds__(256) void scatter_pass_kernel(const int* __restrict__ edges,
        const int* __restrict__ mat, unsigned int* __restrict__ tmp) {
    __shared__ int cur[NBUK];
    int t = threadIdx.x, wg = blockIdx.x;
    for (int j = t; j < NBUK; j += 256) cur[j] = mat[wg * NBUK + j];
    __syncthreads();
    int lo = wg * CHUNK, hi = lo + CHUNK; if (hi > N_EDGES) hi = N_EDGES;
    for (int i = lo + t; i < hi; i += 256) {
        int r = edges[i];
        int c = edges[N_EDGES + i];
        int pos = atomicAdd(&cur[r >> BSH], 1);
        tmp[pos] = (unsigned int)c | ((unsigned int)(r & (BROWS - 1)) << 17);
    }
}

// pass 2: one workgroup per bucket; LDS cursor per row. Output keeps the low
// 6 row bits packed with col (col 17b | row%64 << 17) for layerA's flat stream.
__global__ __launch_bounds__(256) void binsort_kernel(const unsigned int* __restrict__ tmp,
        const int* __restrict__ rs, int* __restrict__ scol, int n) {
    __shared__ int lcur[BROWS];
    int b = blockIdx.x;
    int t = threadIdx.x;
    int r0 = b << BSH;
    int rend = r0 + BROWS; if (rend > n) rend = n;
    for (int j = t; j < BROWS; j += 256) {
        int r = r0 + j;
        lcur[j] = (r < n) ? rs[r] : 0;
    }
    __syncthreads();
    int base = rs[r0];
    int end = rs[rend];
    for (int i = base + t; i < end; i += 256) {
        unsigned int p = tmp[i];
        int pos = atomicAdd(&lcur[p >> 17], 1);
        scol[pos] = (int)(p & 0x7FFFFFu);   // col | (row%64)<<17 (buckets 64-aligned)
    }
}

// fc0 as classic LDS-tiled fp32 GEMM: [N,128]@[128,64] + bias, relu, bf16 twin.
__global__ __launch_bounds__(256, 4) void fc0_kernel(const float* __restrict__ x,
        const float* __restrict__ W0, const float* __restrict__ b0,
        const float* __restrict__ dinv, float* __restrict__ out,
        unsigned short* __restrict__ g, int n) {
    __shared__ float At[64][68];   // x^T slice: At[k][r]
    __shared__ float Bt[64][68];   // W0 slice:  Bt[k][c]
    int t = threadIdx.x;
    int base = blockIdx.x * 64;
    int tx = t & 15, ty = t >> 4;
    int r0 = ty * 4, c0 = tx * 4;
    float acc[4][4] = {{0.f}};
    for (int kc = 0; kc < IN_F; kc += 64) {
        __syncthreads();
#pragma unroll
        for (int i = 0; i < 4; ++i) {           // stage x tile (64 rows x 64 k)
            int idx = (i * 256 + t) * 4;
            int r = idx >> 6, kk = idx & 63;
            int rr = base + r; if (rr >= n) rr = n - 1;
            float4 v = *(const float4*)(x + (size_t)rr * IN_F + kc + kk);
            At[kk][r] = v.x; At[kk + 1][r] = v.y; At[kk + 2][r] = v.z; At[kk + 3][r] = v.w;
        }
#pragma unroll
        for (int i = 0; i < 4; ++i) {           // stage W0 slice (64 k x 64 c)
            int idx = (i * 256 + t) * 4;
            int k = idx >> 6, c = idx & 63;
            float4 v = *(const float4*)(W0 + (size_t)(kc + k) * HID + c);
            Bt[k][c] = v.x; Bt[k][c + 1] = v.y; Bt[k][c + 2] = v.z; Bt[k][c + 3] = v.w;
        }
        __syncthreads();
#pragma unroll 4
        for (int k = 0; k < 64; ++k) {
            float4 a = *(const float4*)&At[k][r0];
            float4 b = *(const float4*)&Bt[k][c0];
            acc[0][0] += a.x * b.x; acc[0][1] += a.x * b.y; acc[0][2] += a.x * b.z; acc[0][3] += a.x * b.w;
            acc[1][0] += a.y * b.x; acc[1][1] += a.y * b.y; acc[1][2] += a.y * b.z; acc[1][3] += a.y * b.w;
            acc[2][0] += a.z * b.x; acc[2][1] += a.z * b.y; acc[2][2] += a.z * b.z; acc[2][3] += a.z * b.w;
            acc[3][0] += a.w * b.x; acc[3][1] += a.w * b.y; acc[3][2] += a.w * b.z; acc[3][3] += a.w * b.w;
        }
    }
    float4 bias = *(const float4*)(b0 + c0);
#pragma unroll
    for (int i = 0; i < 4; ++i) {
        int r = base + r0 + i;
        if (r < n) {
            float v0 = acc[i][0] + bias.x; v0 = v0 > 0.f ? v0 : 0.f;
            float v1 = acc[i][1] + bias.y; v1 = v1 > 0.f ? v1 : 0.f;
            float v2 = acc[i][2] + bias.z; v2 = v2 > 0.f ? v2 : 0.f;
            float v3 = acc[i][3] + bias.w; v3 = v3 > 0.f ? v3 : 0.f;
            *(float4*)(out + (size_t)r * HID + c0) = make_float4(v0, v1, v2, v3);
            float dr = dinv[r];
            ushort4 gu;
            gu.x = f2b(dr * v0); gu.y = f2b(dr * v1);
            gu.z = f2b(dr * v2); gu.w = f2b(dr * v3);
            *(ushort4*)(g + (size_t)r * HID + c0) = gu;
        }
    }
}

// fused per-layer kernel, v4: flat edge stream + register accumulation
// (R5 structure) with LDS cut to 19.5KB: cw is read straight from global
// (16KB, L1-resident, wave-coalesced float4) instead of staged into LDS.
// 8 blocks/CU -> 100% wave occupancy for the latency-bound gather phase.
__global__ __launch_bounds__(256, 8) void layerA_kernel(
        const unsigned short* __restrict__ g, const float* __restrict__ x0,
        const float* __restrict__ dinv, const int* __restrict__ rs,
        const int* __restrict__ scol, const float* __restrict__ cw,
        float* __restrict__ hout, float* __restrict__ stats, float beta, int n) {
    __shared__ float At[64][68];   // s^T tile: At[k][r]
    __shared__ float redS[4][64];
    __shared__ float redQ[4][64];
    int t = threadIdx.x;
    int wave = t >> 6, lane = t & 63;
    int base = blockIdx.x * 64;

    // zero the accumulator tile (covers zero-degree rows)
    {
        float* a = &At[0][0];
        for (int i = t; i < 64 * 68; i += 256) a[i] = 0.f;
    }
    __syncthreads();

    // flat-stream gather, register accumulation
    {
        int q = lane >> 4, l = lane & 15;
        int rq = base + wave * 16 + q * 4;       // first row of this quarter
        int rqe = rq + 4;
        if (rq > n) rq = n;
        if (rqe > n) rqe = n;
        int e = rs[rq], eend = rs[rqe];
        float4 acc4 = make_float4(0.f, 0.f, 0.f, 0.f);
        int cur = -1;
        for (; e < eend; e += 8) {
            unsigned int pk[8];
            ushort4 gv[8];
#pragma unroll
            for (int j = 0; j < 8; ++j) {
                int ee = e + j;
                pk[j] = (unsigned int)scol[ee < eend ? ee : eend - 1];
            }
#pragma unroll
            for (int j = 0; j < 8; ++j)
                gv[j] = *(const ushort4*)(g + (size_t)(pk[j] & 0x1FFFFu) * HID + l * 4);
#pragma unroll
            for (int j = 0; j < 8; ++j) {
                if (e + j < eend) {
                    int rj = (int)(pk[j] >> 17);
                    if (rj != cur) {
                        if (cur >= 0) {
                            At[l * 4 + 0][cur] = acc4.x;
                            At[l * 4 + 1][cur] = acc4.y;
                            At[l * 4 + 2][cur] = acc4.z;
                            At[l * 4 + 3][cur] = acc4.w;
                        }
                        acc4 = make_float4(0.f, 0.f, 0.f, 0.f);
                        cur = rj;
                    }
                    acc4.x += b2f(gv[j].x);
                    acc4.y += b2f(gv[j].y);
                    acc4.z += b2f(gv[j].z);
                    acc4.w += b2f(gv[j].w);
                }
            }
        }
        if (cur >= 0) {
            At[l * 4 + 0][cur] = acc4.x;
            At[l * 4 + 1][cur] = acc4.y;
            At[l * 4 + 2][cur] = acc4.z;
            At[l * 4 + 3][cur] = acc4.w;
        }
    }
    __syncthreads();

    // fix-up: s = (1-a)*dinv[r]*agg + a*x0[r]
    {
        int rl0 = wave * 16;
#pragma unroll
        for (int i = 0; i < 16; ++i) {
            int rl = rl0 + i;
            int r = base + rl;
            if (r < n) {
                At[lane][rl] = (1.f - ALPHA) * dinv[r] * At[lane][rl]
                             + ALPHA * x0[(size_t)r * HID + lane];
            }
        }
    }
    __syncthreads();

    int tx = t & 15, ty = t >> 4;
    int r0 = ty * 4, c0 = tx * 4;
    float acc[4][4] = {{0.f}};
#pragma unroll 4
    for (int k = 0; k < 64; ++k) {
        float4 a = *(const float4*)&At[k][r0];
        float4 b = *(const float4*)(cw + (size_t)k * HID + c0);   // L1-resident
        acc[0][0] += a.x * b.x; acc[0][1] += a.x * b.y; acc[0][2] += a.x * b.z; acc[0][3] += a.x * b.w;
        acc[1][0] += a.y * b.x; acc[1][1] += a.y * b.y; acc[1][2] += a.y * b.z; acc[1][3] += a.y * b.w;
        acc[2][0] += a.z * b.x; acc[2][1] += a.z * b.y; acc[2][2] += a.z * b.z; acc[2][3] += a.z * b.w;
        acc[3][0] += a.w * b.x; acc[3][1] += a.w * b.y; acc[3][2] += a.w * b.z; acc[3][3] += a.w * b.w;
    }
    float lsum[4] = {0.f, 0.f, 0.f, 0.f}, lsq[4] = {0.f, 0.f, 0.f, 0.f};
    float ob = 1.f - beta;
#pragma unroll
    for (int i = 0; i < 4; ++i) {
        int r = base + r0 + i;
        if (r < n) {
            float h0 = ob * At[c0][r0 + i]     + beta * acc[i][0];
            float h1 = ob * At[c0 + 1][r0 + i] + beta * acc[i][1];
            float h2 = ob * At[c0 + 2][r0 + i] + beta * acc[i][2];
            float h3 = ob * At[c0 + 3][r0 + i] + beta * acc[i][3];
            *(float4*)(hout + (size_t)r * HID + c0) = make_float4(h0, h1, h2, h3);
            lsum[0] += h0; lsq[0] += h0 * h0;
            lsum[1] += h1; lsq[1] += h1 * h1;
            lsum[2] += h2; lsq[2] += h2 * h2;
            lsum[3] += h3; lsq[3] += h3 * h3;
        }
    }
    // reduce across the 16 threads sharing tx: lanes {tx, tx+16, tx+32, tx+48}
#pragma unroll
    for (int j = 0; j < 4; ++j) {
        float s = lsum[j], q = lsq[j];
        s += __shfl_xor(s, 16, 64); s += __shfl_xor(s, 32, 64);
        q += __shfl_xor(q, 16, 64); q += __shfl_xor(q, 32, 64);
        lsum[j] = s; lsq[j] = q;
    }
    __syncthreads();
    if (lane < 16) {
#pragma unroll
        for (int j = 0; j < 4; ++j) {
            redS[wave][lane * 4 + j] = lsum[j];
            redQ[wave][lane * 4 + j] = lsq[j];
        }
    }
    __syncthreads();
    if (t < 64) {
        float s = redS[0][t] + redS[1][t] + redS[2][t] + redS[3][t];
        float q = redQ[0][t] + redQ[1][t] + redQ[2][t] + redQ[3][t];
        atomicAdd(&stats[t], s);
        atomicAdd(&stats[64 + t], q);
    }
}

// BN + residual + relu in place; also writes next-layer gather twin
__global__ void layerB_kernel(float4* __restrict__ h, const float4* __restrict__ xprev,
        const float* __restrict__ stats, const float* __restrict__ gamma,
        const float* __restrict__ bnb, const float* __restrict__ dinv,
        ushort4* __restrict__ g, int total4) {
    int i = blockIdx.x * blockDim.x + threadIdx.x;
    if (i >= total4) return;
    int fb = (i & 15) * 4;
    int row = i >> 4;
    float dr = dinv[row];
    float4 hv = h[i];
    float4 xp = xprev[i];
    float o[4];
    float hin[4] = { hv.x, hv.y, hv.z, hv.w };
    float xin[4] = { xp.x, xp.y, xp.z, xp.w };
#pragma unroll
    for (int j = 0; j < 4; ++j) {
        int f = fb + j;
        float mu = stats[f] * (1.0f / N_NODES);
        float var = stats[64 + f] * (1.0f / N_NODES) - mu * mu;
        if (var < 0.f) var = 0.f;
        float inv = rsqrtf(var + BN_EPS);
        float v = (hin[j] - mu) * inv * gamma[f] + bnb[f] + xin[j];
        o[j] = v > 0.f ? v : 0.f;
    }
    h[i] = make_float4(o[0], o[1], o[2], o[3]);
    ushort4 gu;
    gu.x = f2b(dr * o[0]); gu.y = f2b(dr * o[1]);
    gu.z = f2b(dr * o[2]); gu.w = f2b(dr * o[3]);
    g[i] = gu;
}

// out = x @ W1 + b1 as LDS-tiled GEMM (K=64, single chunk) + bias epilogue.
__global__ __launch_bounds__(256, 4) void final_kernel(const float* __restrict__ xcur,
        const float* __restrict__ W1, const float* __restrict__ b1,
        float* __restrict__ out, int n) {
    __shared__ float At[64][68];   // x^T tile: At[k][r]
    __shared__ float Bt[64][68];   // W1:       Bt[k][c]
    int t = threadIdx.x;
    int base = blockIdx.x * 64;
    int tx = t & 15, ty = t >> 4;
    int r0 = ty * 4, c0 = tx * 4;
#pragma unroll
    for (int i = 0; i < 4; ++i) {               // stage W1 (64x64)
        int idx = (i * 256 + t) * 4;
        int k = idx >> 6, c = idx & 63;
        float4 v = *(const float4*)(W1 + (size_t)k * OUT_F + c);
        Bt[k][c] = v.x; Bt[k][c + 1] = v.y; Bt[k][c + 2] = v.z; Bt[k][c + 3] = v.w;
    }
#pragma unroll
    for (int i = 0; i < 4; ++i) {               // stage x tile transposed
        int idx = (i * 256 + t) * 4;
        int r = idx >> 6, kk = idx & 63;
        int rr = base + r; if (rr >= n) rr = n - 1;
        float4 v = *(const float4*)(xcur + (size_t)rr * HID + kk);
        At[kk][r] = v.x; At[kk + 1][r] = v.y; At[kk + 2][r] = v.z; At[kk + 3][r] = v.w;
    }
    __syncthreads();
    float acc[4][4] = {{0.f}};
#pragma unroll 4
    for (int k = 0; k < 64; ++k) {
        float4 a = *(const float4*)&At[k][r0];
        float4 b = *(const float4*)&Bt[k][c0];
        acc[0][0] += a.x * b.x; acc[0][1] += a.x * b.y; acc[0][2] += a.x * b.z; acc[0][3] += a.x * b.w;
        acc[1][0] += a.y * b.x; acc[1][1] += a.y * b.y; acc[1][2] += a.y * b.z; acc[1][3] += a.y * b.w;
        acc[2][0] += a.z * b.x; acc[2][1] += a.z * b.y; acc[2][2] += a.z * b.z; acc[2][3] += a.z * b.w;
        acc[3][0] += a.w * b.x; acc[3][1] += a.w * b.y; acc[3][2] += a.w * b.z; acc[3][3] += a.w * b.w;
    }
    float4 bias = *(const float4*)(b1 + c0);
#pragma unroll
    for (int i = 0; i < 4; ++i) {
        int r = base + r0 + i;
        if (r < n) {
            *(float4*)(out + (size_t)r * OUT_F + c0) = make_float4(
                acc[i][0] + bias.x, acc[i][1] + bias.y,
                acc[i][2] + bias.z, acc[i][3] + bias.w);
        }
    }
}

extern "C" void kernel_launch(void* const* d_in, const int* in_sizes, int n_in,
                              void* d_out, int out_size, void* d_ws, size_t ws_size,
                              hipStream_t stream) {
    const float* x     = (const float*)d_in[0];
    const int*   edges = (const int*)d_in[1];
    const float* W0    = (const float*)d_in[2];
    const float* b0    = (const float*)d_in[3];
    const float* cw    = (const float*)d_in[4];
    const float* gamma = (const float*)d_in[5];
    const float* bnb   = (const float*)d_in[6];
    const float* W1    = (const float*)d_in[7];
    const float* b1    = (const float*)d_in[8];
    float* out = (float*)d_out;

    char* ws = (char*)d_ws;
    float* x0    = (float*)(ws + OFF_X0);
    float* bufA  = (float*)(ws + OFF_HA);
    float* bufB  = (float*)(ws + OFF_HB);
    unsigned int* tmp = (unsigned int*)(ws + OFF_HB + OFF_TMP_REL);  // dead before layer loop
    int*   mat   = (int*)(ws + OFF_HB + OFF_MAT_REL);                // dead before layer loop
    unsigned short* gbuf = (unsigned short*)(ws + OFF_GB);
    int*   scol  = (int*)(ws + OFF_SORTED);
    int*   cnt   = (int*)(ws + OFF_CNT);
    float* stats = (float*)(ws + OFF_STATS);
    float* dinv  = (float*)(ws + OFF_DINV);
    int*   rs    = (int*)(ws + OFF_ROWSTART);
    int*   bsum  = (int*)(ws + OFF_BSUM);

    hipMemsetAsync(ws + ZERO_OFF, 0, ZERO_BYTES, stream);
    hist2_kernel<<<P_SCAT, 256, 0, stream>>>(edges, cnt, mat);
    dinv_kernel<<<(N_NODES + 255) / 256, 256, 0, stream>>>(cnt, dinv, N_NODES);
    blocksum_kernel<<<NSCAN_BLOCKS, SCAN_BLK, 0, stream>>>(cnt, bsum, N_NODES);
    scan_bsum_kernel<<<1, 512, 0, stream>>>(bsum, NSCAN_BLOCKS);
    scan_write_kernel<<<NSCAN_BLOCKS, SCAN_BLK, 0, stream>>>(cnt, bsum, rs, N_NODES);
    matscan_kernel<<<NBUK, 256, 0, stream>>>(rs, mat);
    scatter_pass_kernel<<<P_SCAT, 256, 0, stream>>>(edges, mat, tmp);
    binsort_kernel<<<NBUK, 256, 0, stream>>>(tmp, rs, scol, N_NODES);
    fc0_kernel<<<(N_NODES + 63) / 64, 256, 0, stream>>>(x, W0, b0, dinv, x0, gbuf, N_NODES);

    const float* xc = x0;
    float* bufs[2] = { bufA, bufB };
    for (int i = 0; i < NLAYERS; ++i) {
        float beta = logf(0.5f / (float)(i + 1) + 1.0f);
        float* hb = bufs[i & 1];
        layerA_kernel<<<NBLK, 256, 0, stream>>>(gbuf, x0, dinv, rs, scol,
                cw + (size_t)i * HID * HID, hb, stats + i * 128, beta, N_NODES);
        layerB_kernel<<<(N_NODES * HID / 4 + 255) / 256, 256, 0, stream>>>(
                (float4*)hb, (const float4*)xc,
                stats + i * 128, gamma + i * HID, bnb + i * HID, dinv,
                (ushort4*)gbuf, N_NODES * HID / 4);
        xc = hb;
    }
    final_kernel<<<(N_NODES + 63) / 64, 256, 0, stream>>>(xc, W1, b1, out, N_NODES);
}